// Round 6
// baseline (7747.739 us; speedup 1.0000x reference)
//
#include <hip/hip_runtime.h>

typedef _Float16 half8 __attribute__((ext_vector_type(8)));
typedef float f32x4 __attribute__((ext_vector_type(4)));
typedef unsigned uint4v __attribute__((ext_vector_type(4)));

#define BB 64
#define SS 512
#define DD 512
#define HH 1024
#define KK 1536
#define PKU4 12288           // packets per buffer: 64 rows * 64 blocks * 3, in uint4

#define MFMA(a, b, c) __builtin_amdgcn_mfma_f32_16x16x32_f16(a, b, c, 0, 0, 0)

// x-region fragment permutation (h-region is identity on both operands; the
// shared permutation cancels inside the MFMA dot product).
__device__ __host__ __forceinline__ int kperm(int k) {
  int blk = k >> 5, r = k & 31;
  return (blk << 5) | (((r >> 2) & 3) << 3) | ((r >> 4) << 2) | (r & 3);
}

// Pack weights: Wp[p][k'] fp16, p = b*80 + tile*16 + c  (tile: 0=g,1=r,2=z,3=i_n,4=h_n)
__global__ void prep_w(const float* __restrict__ Wg, const float* __restrict__ Wih,
                       const float* __restrict__ Whh, _Float16* __restrict__ Wp) {
  int p = blockIdx.x;                       // 0..5119
  int b = p / 80, rem = p % 80, t = rem >> 4, c = rem & 15;
  int j = b * 16 + c;
  for (int pass = 0; pass < 6; ++pass) {
    int k = pass * 256 + threadIdx.x;
    float v;
    if (t == 0)      v = Wg[k * HH + j];
    else if (t == 1) v = (k < DD) ? Wih[k * 3 * HH + j]          : Whh[(k - DD) * 3 * HH + j];
    else if (t == 2) v = (k < DD) ? Wih[k * 3 * HH + HH + j]     : Whh[(k - DD) * 3 * HH + HH + j];
    else if (t == 3) v = (k < DD) ? Wih[k * 3 * HH + 2 * HH + j] : 0.f;
    else             v = (k < DD) ? 0.f : Whh[(k - DD) * 3 * HH + 2 * HH + j];
    int pos = (k < DD) ? kperm(k) : k;      // x: kperm'd, h: identity
    Wp[(size_t)p * KK + pos] = (_Float16)v;
  }
}

// Xh[t][sg][row][lkg][8]: fp16 x in fragment-ready order (sg = x k-step 0..15)
__global__ void prep_xh(const float* __restrict__ x, _Float16* __restrict__ Xh) {
  int t = blockIdx.x, sg = blockIdx.y;
  int row = threadIdx.x >> 2, lkg = threadIdx.x & 3;
  const float* xp = x + ((size_t)row * SS + t) * DD + sg * 32 + lkg * 4;
  half8 hv;
#pragma unroll
  for (int j = 0; j < 4; ++j) { hv[j] = (_Float16)xp[j]; hv[4 + j] = (_Float16)xp[16 + j]; }
  *(half8*)(Xh + ((((size_t)t * 16 + sg) * 64 + row) * 4 + lkg) * 8) = hv;
}

// ---- packet helpers -------------------------------------------------------
// Packet (row, producer p, s) at uint4 index (row*64+p)*3+s:
//   s=0: halfs = h[row][16p+0..5]   s=1: h[row][16p+6..11]   s=2: h[row][16p+12..15],0,0
//   dword3 = tag (step that published this h). Consumer fragment = 8 consecutive
//   cols starting at col0 = 16p + (lkg&1)*8:
//   lkg even: pkts (s0,s1): frag dwords = {P0.x,P0.y,P0.z,P1.x}
//   lkg odd : pkts (s1,s2): frag dwords = {P0.y,P0.z,P1.x,P1.y}

template<int KB>
__device__ __forceinline__ void issue_pk(const uint4v* __restrict__ Pb, int w, int lrow,
                                         int lkg, uint4v (&P0)[4], uint4v (&P1)[4]) {
#pragma unroll
  for (int mt = 0; mt < 4; ++mt) {
    const int p = (w * 8 + KB) * 2 + (lkg >> 1);
    const uint4v* ap = Pb + ((size_t)((mt * 16 + lrow) * 64 + p) * 3 + (lkg & 1));
    asm volatile("global_load_dwordx4 %0, %2, off sc0 sc1\n\t"
                 "global_load_dwordx4 %1, %2, off offset:16 sc0 sc1"
                 : "=&v"(P0[mt]), "=&v"(P1[mt]) : "v"(ap) : "memory");
  }
}

__device__ __forceinline__ int tags_ok(const uint4v (&P0)[4], const uint4v (&P1)[4],
                                       unsigned want) {
  unsigned bad = 0;
#pragma unroll
  for (int f = 0; f < 4; ++f) bad |= (P0[f][3] ^ want) | (P1[f][3] ^ want);
  return __all(bad == 0);
}

template<int KB>
__device__ __forceinline__ void compute_pk(const uint4v (&P0)[4], const uint4v (&P1)[4],
                                           int lkg, const half8 (&bh)[3][8],
                                           const half8 (&b4)[8], f32x4 (&acc)[5][4]) {
  const int odd = lkg & 1;
#pragma unroll
  for (int mt = 0; mt < 4; ++mt) {
    uint4v fv;
    fv[0] = odd ? P0[mt][1] : P0[mt][0];
    fv[1] = odd ? P0[mt][2] : P0[mt][1];
    fv[2] = odd ? P1[mt][0] : P0[mt][2];
    fv[3] = odd ? P1[mt][1] : P1[mt][0];
    half8 af = __builtin_bit_cast(half8, fv);
    acc[0][mt] = MFMA(af, bh[0][KB], acc[0][mt]);
    acc[1][mt] = MFMA(af, bh[1][KB], acc[1][mt]);
    acc[2][mt] = MFMA(af, bh[2][KB], acc[2][mt]);
    acc[4][mt] = MFMA(af, b4[KB], acc[4][mt]);
  }
}

#define WAITV(lit) do { asm volatile("s_waitcnt vmcnt(" lit ")" ::: "memory"); \
                        __builtin_amdgcn_sched_barrier(0); } while (0)
#define RETRY(KB, P0a, P1a) do { \
    if (!tags_ok(P0a, P1a, want)) { \
      do { issue_pk<KB>(Pb, w, lrow, lkg, P0a, P1a); WAITV("0"); } \
      while (!tags_ok(P0a, P1a, want)); } } while (0)

__global__ __launch_bounds__(256, 1) void rnn_seq(
    const _Float16* __restrict__ Xh, const _Float16* __restrict__ Wp,
    const float* __restrict__ bg, const float* __restrict__ bih,
    const float* __restrict__ bhh, float* __restrict__ out,
    uint4v* __restrict__ Pk, uint4v* __restrict__ sink) {
  const int blk = blockIdx.x;
  const int tid = threadIdx.x;
  const int w = tid >> 6;              // wave 0..3 (K-split)
  const int lane = tid & 63;
  const int lrow = lane & 15;
  const int lkg = lane >> 4;

  __shared__ float Red[2][80][68];               // 43,520 B
  __shared__ alignas(16) _Float16 Hst[64][16];   //  2,048 B
  __shared__ alignas(16) _Float16 Xstage[64 * 512];  // 65,536 B  (total ~111 KB)

  const int ej = tid & 15;
  const int rq = tid >> 4;             // 0..15 -> rows rq*4..rq*4+3
  const int ghcol = blk * 16 + ej;
  const float bg_b  = bg[ghcol];
  const float br_b  = bih[ghcol] + bhh[ghcol];
  const float bz_b  = bih[HH + ghcol] + bhh[HH + ghcol];
  const float bin_b = bih[2 * HH + ghcol];
  const float bhn_b = bhh[2 * HH + ghcol];
  float hreg[4] = {0.f, 0.f, 0.f, 0.f};

  // ---- all weights register-resident (48 half8 = 192 VGPR) ----
  // x: k-steps w*4+kk (kk 0..3); h: k-steps 16 + w*8 + kk (kk 0..7)
  half8 bx[3][4], b3[4], bh[3][8], b4[8];
#pragma unroll
  for (int tt = 0; tt < 3; ++tt)
#pragma unroll
    for (int kk = 0; kk < 4; ++kk)
      bx[tt][kk] = *(const half8*)(Wp + (size_t)(blk * 80 + tt * 16 + lrow) * KK + (w * 4 + kk) * 32 + lkg * 8);
#pragma unroll
  for (int kk = 0; kk < 4; ++kk)
    b3[kk] = *(const half8*)(Wp + (size_t)(blk * 80 + 48 + lrow) * KK + (w * 4 + kk) * 32 + lkg * 8);
#pragma unroll
  for (int tt = 0; tt < 3; ++tt)
#pragma unroll
    for (int kk = 0; kk < 8; ++kk)
      bh[tt][kk] = *(const half8*)(Wp + (size_t)(blk * 80 + tt * 16 + lrow) * KK + (16 + w * 8 + kk) * 32 + lkg * 8);
#pragma unroll
  for (int kk = 0; kk < 8; ++kk)
    b4[kk] = *(const half8*)(Wp + (size_t)(blk * 80 + 64 + lrow) * KK + (16 + w * 8 + kk) * 32 + lkg * 8);

  // prefetch Xstage(t=0)
#pragma unroll
  for (int kk = 0; kk < 4; ++kk)
#pragma unroll
    for (int mt = 0; mt < 4; ++mt) {
      const _Float16* gsrc = Xh + ((((size_t)0 * 16 + (w * 4 + kk)) * 64 + (mt * 16 + lrow)) * 4 + lkg) * 8;
      __builtin_amdgcn_global_load_lds(
          (const __attribute__((address_space(1))) void*)gsrc,
          (__attribute__((address_space(3))) void*)(Xstage + (w * 16 + kk * 4 + mt) * 512), 16, 0, 0);
    }
  WAITV("0");   // weights + Xstage(0) resident; compiler's VMEM queue now empty

  for (int t = 0; t < SS; ++t) {
    const uint4v* Pb = Pk + (size_t)(t & 1) * PKU4;
    uint4v* Pn = Pk + (size_t)((t + 1) & 1) * PKU4;
    const unsigned want = (unsigned)t;

    f32x4 zz = {0.f, 0.f, 0.f, 0.f};
    f32x4 acc[5][4];
#pragma unroll
    for (int tt = 0; tt < 5; ++tt)
#pragma unroll
      for (int mt = 0; mt < 4; ++mt) acc[tt][mt] = zz;

    // ---- issue first 4 packet batches; their RT overlaps the x-phase ----
    uint4v A0[4], A1[4], B0[4], B1[4], C0[4], C1[4], D0[4], D1[4];
    issue_pk<0>(Pb, w, lrow, lkg, A0, A1);
    issue_pk<1>(Pb, w, lrow, lkg, B0, B1);
    issue_pk<2>(Pb, w, lrow, lkg, C0, C1);
    issue_pk<3>(Pb, w, lrow, lkg, D0, D1);

    // ---- x-part from LDS (prefetched; DS-only, no vmcnt traffic) ----
#pragma unroll
    for (int kk = 0; kk < 4; ++kk) {
      half8 afr[4];
#pragma unroll
      for (int mt = 0; mt < 4; ++mt)
        afr[mt] = *(const half8*)(Xstage + (w * 16 + kk * 4 + mt) * 512 + lane * 8);
#pragma unroll
      for (int mt = 0; mt < 4; ++mt) {
        acc[0][mt] = MFMA(afr[mt], bx[0][kk], acc[0][mt]);
        acc[1][mt] = MFMA(afr[mt], bx[1][kk], acc[1][mt]);
        acc[2][mt] = MFMA(afr[mt], bx[2][kk], acc[2][mt]);
        acc[3][mt] = MFMA(afr[mt], b3[kk], acc[3][mt]);
      }
    }

    // xpref(t+1): after x ds_reads (WAR). tn clamps at last step (harmless re-read).
    {
      const int tn = (t + 1 < SS) ? t + 1 : t;
      asm volatile("s_waitcnt lgkmcnt(0)" ::: "memory");
      __builtin_amdgcn_sched_barrier(0);
#pragma unroll
      for (int kk = 0; kk < 4; ++kk)
#pragma unroll
        for (int mt = 0; mt < 4; ++mt) {
          const _Float16* gsrc = Xh + ((((size_t)tn * 16 + (w * 4 + kk)) * 64 + (mt * 16 + lrow)) * 4 + lkg) * 8;
          __builtin_amdgcn_global_load_lds(
              (const __attribute__((address_space(1))) void*)gsrc,
              (__attribute__((address_space(3))) void*)(Xstage + (w * 16 + kk * 4 + mt) * 512), 16, 0, 0);
        }
    }

    // ---- h-phase: 8 batches, 4 in flight. Wait constants = #ops issued
    // after the target batch (in-order vmcnt retirement makes them exact):
    // queue: [S<=1 old store][P0..P3 32][X 16] then P4..P7 one per batch.
    WAITV("40"); RETRY(0, A0, A1); compute_pk<0>(A0, A1, lkg, bh, b4, acc); issue_pk<4>(Pb, w, lrow, lkg, A0, A1);
    WAITV("40"); RETRY(1, B0, B1); compute_pk<1>(B0, B1, lkg, bh, b4, acc); issue_pk<5>(Pb, w, lrow, lkg, B0, B1);
    WAITV("40"); RETRY(2, C0, C1); compute_pk<2>(C0, C1, lkg, bh, b4, acc); issue_pk<6>(Pb, w, lrow, lkg, C0, C1);
    WAITV("40"); RETRY(3, D0, D1); compute_pk<3>(D0, D1, lkg, bh, b4, acc); issue_pk<7>(Pb, w, lrow, lkg, D0, D1);
    WAITV("24"); RETRY(4, A0, A1); compute_pk<4>(A0, A1, lkg, bh, b4, acc);
    WAITV("16"); RETRY(5, B0, B1); compute_pk<5>(B0, B1, lkg, bh, b4, acc);
    WAITV("8");  RETRY(6, C0, C1); compute_pk<6>(C0, C1, lkg, bh, b4, acc);
    WAITV("0");  RETRY(7, D0, D1); compute_pk<7>(D0, D1, lkg, bh, b4, acc);

    // ---- cross-wave reduction: 4 partials -> 2 slabs -> epilogue sums ----
    if (w >= 2) {
#pragma unroll
      for (int tt = 0; tt < 5; ++tt)
#pragma unroll
        for (int mt = 0; mt < 4; ++mt)
          *(f32x4*)&Red[w - 2][tt * 16 + lrow][mt * 16 + lkg * 4] = acc[tt][mt];
    }
    __syncthreads();
    if (w < 2) {
#pragma unroll
      for (int tt = 0; tt < 5; ++tt)
#pragma unroll
        for (int mt = 0; mt < 4; ++mt) {
          f32x4* p = (f32x4*)&Red[w][tt * 16 + lrow][mt * 16 + lkg * 4];
          *p = *p + acc[tt][mt];
        }
    }
    __syncthreads();

    // ---- epilogue: 256 threads, 4 rows x 1 col ----
    {
      f32x4 s[5];
#pragma unroll
      for (int g = 0; g < 5; ++g)
        s[g] = *(const f32x4*)&Red[0][g * 16 + ej][rq * 4] +
               *(const f32x4*)&Red[1][g * 16 + ej][rq * 4];
#pragma unroll
      for (int r = 0; r < 4; ++r) {
        float g_ = 1.f / (1.f + __expf(-(s[0][r] + bg_b)));
        float r_ = 1.f / (1.f + __expf(-(s[1][r] + br_b)));
        float z_ = 1.f / (1.f + __expf(-(s[2][r] + bz_b)));
        float n_ = tanhf(s[3][r] + bin_b + r_ * (s[4][r] + bhn_b));
        float h = g_ * ((1.f - z_) * n_ + z_ * hreg[r]);
        hreg[r] = h;
        int row = rq * 4 + r;
        if (t == SS - 1) out[row * HH + ghcol] = h;
        else             Hst[row][ej] = (_Float16)h;
      }
    }

    // ---- publish: fire-and-forget tagged packets (no drain, no flag) ----
    if (t < SS - 1) {
      __syncthreads();                 // Hst complete
      const int prow = tid >> 2, ps = tid & 3;   // 64 rows x {3 packets + 1 dummy}
      uint4v lo = *(const uint4v*)&Hst[prow][0];
      uint4v hi = *(const uint4v*)&Hst[prow][8];
      uint4v pk;
      if (ps == 0)      { pk[0] = lo[0]; pk[1] = lo[1]; pk[2] = lo[2]; }
      else if (ps == 1) { pk[0] = lo[3]; pk[1] = hi[0]; pk[2] = hi[1]; }
      else              { pk[0] = hi[2]; pk[1] = hi[3]; pk[2] = 0u;    }
      pk[3] = (unsigned)(t + 1);
      uint4v* dst = (ps < 3) ? (Pn + ((size_t)(prow * 64 + blk) * 3 + ps))
                             : (sink + (size_t)(blk * 256 + tid));   // uniform 1 store/thread
      asm volatile("global_store_dwordx4 %0, %1, off sc0 sc1" :: "v"(dst), "v"(pk) : "memory");
    }
  }
}

extern "C" void kernel_launch(void* const* d_in, const int* in_sizes, int n_in,
                              void* d_out, int out_size, void* d_ws, size_t ws_size,
                              hipStream_t stream) {
  const float* x   = (const float*)d_in[0];
  const float* Wg  = (const float*)d_in[1];
  const float* bg  = (const float*)d_in[2];
  const float* Wih = (const float*)d_in[3];
  const float* bih = (const float*)d_in[4];
  const float* Whh = (const float*)d_in[5];
  const float* bhh = (const float*)d_in[6];
  // d_in[7..10] (Wa, ba, Ws, bs) are mathematically dead: softmax over size-1 axis == 1
  float* out = (float*)d_out;

  char* ws = (char*)d_ws;
  _Float16* Wp   = (_Float16*)ws;                        // 15,728,640 B
  _Float16* Xh   = (_Float16*)(ws + 15728640);           // 33,554,432 B
  uint4v*   Pk   = (uint4v*)(ws + 15728640 + 33554432);  // 2*196,608 = 393,216 B
  uint4v*   sink = (uint4v*)(ws + 15728640 + 33554432 + 393216);  // 262,144 B

  hipMemsetAsync((void*)Pk, 0, 393216, stream);          // tag 0 == h(0) = 0
  prep_w<<<5120, 256, 0, stream>>>(Wg, Wih, Whh, Wp);
  prep_xh<<<dim3(512, 16), 256, 0, stream>>>(x, Xh);
  rnn_seq<<<64, 256, 0, stream>>>(Xh, Wp, bg, bih, bhh, out, Pk, sink);
}